// Round 5
// baseline (216.813 us; speedup 1.0000x reference)
//
#include <hip/hip_runtime.h>

#define B_    2
#define T_    2048
#define C_    1024
#define H_    16
#define HD_   64
#define MEM_  256
#define S_    2304   // MEM + T
#define NKT_  36     // S_/64 k-tiles

typedef __attribute__((ext_vector_type(8))) short short8;   // 8 bf16 = 4 VGPRs
typedef __attribute__((ext_vector_type(4))) short short4v;  // 4 bf16 = 2 VGPRs
typedef __attribute__((ext_vector_type(4))) float f32x4;

// round-half-up bf16 (2 VALU ops; tie behavior irrelevant here)
__device__ __forceinline__ unsigned short f2bf(float x) {
    return (unsigned short)((__float_as_uint(x) + 0x8000u) >> 16);
}

// pack 2 floats -> 2 bf16 in one VGPR (round-half-up): 2 adds + 1 v_perm
__device__ __forceinline__ unsigned int pk2bf(float lo, float hi) {
    unsigned int a = __float_as_uint(lo) + 0x8000u;
    unsigned int b = __float_as_uint(hi) + 0x8000u;
    return __builtin_amdgcn_perm(b, a, 0x07060302);  // {b.hi16, a.hi16}
}

typedef const __attribute__((address_space(1))) unsigned int* gp_t;
typedef __attribute__((address_space(3))) unsigned int* lp_t;

// async global->LDS, 16B/lane. g per-lane (base + lane*8 ushorts), l wave-uniform.
__device__ __forceinline__ void gll16(const unsigned short* g, unsigned short* l) {
    __builtin_amdgcn_global_load_lds((gp_t)g, (lp_t)l, 16, 0, 0);
}

// ---------------------------------------------------------------------------
// Merged prep: job by flat blockIdx.
//  [0,4096)       convert x  -> x_tl  tile-major swizzled [mt][kc][128][32]
//  [4096,4864)    transpose W_attn -> WtA [nt][kc][128][32]
//  [4864,5120)    transpose W_proj -> WtP
//  [5120,7168)    ext_mem -> k_ws rows 0..MEM (row-swz), v_tl tiles 0..3 (swz)
// ---------------------------------------------------------------------------
__global__ __launch_bounds__(256) void prep_all(
    const float* __restrict__ x, const float* __restrict__ Wa,
    const float* __restrict__ Wp, const float* __restrict__ ext,
    unsigned short* __restrict__ x_tl, unsigned short* __restrict__ WtA,
    unsigned short* __restrict__ WtP, unsigned short* __restrict__ k_ws,
    unsigned short* __restrict__ v_tl)
{
    __shared__ float L[64][65];
    const int bid = blockIdx.x, tid = threadIdx.x;
    if (bid < 4096) {
        int i = bid * 256 + tid;                  // over 1,048,576 float4
        int c = (i & 255) * 4;
        int m = i >> 8;
        float4 v = ((const float4*)x)[i];
        ushort4 o;
        o.x = f2bf(v.x); o.y = f2bf(v.y); o.z = f2bf(v.z); o.w = f2bf(v.w);
        int mt = m >> 7, r = m & 127, kc = c >> 5, cc = c & 31;
        int p = (cc >> 3) ^ ((r >> 1) & 3);
        *(ushort4*)&x_tl[(((size_t)mt * 32 + kc) << 12) + (r << 5) + p * 8 + (cc & 7)] = o;
    } else if (bid < 5120) {
        const float* in; unsigned short* out; int Cc, r0, c0;
        if (bid < 4864) {
            int r = bid - 4096; in = Wa; out = WtA; Cc = 3 * C_;
            c0 = (r % 48) * 64; r0 = (r / 48) * 64;
        } else {
            int r = bid - 4864; in = Wp; out = WtP; Cc = C_;
            c0 = (r & 15) * 64; r0 = (r >> 4) * 64;
        }
        const int jj = tid >> 4;
        const int i4 = (tid & 15) * 4;
#pragma unroll
        for (int t = 0; t < 4; ++t) {
            int j = jj + t * 16;
            float4 v = *(const float4*)(in + (size_t)(r0 + j) * Cc + c0 + i4);
            L[i4 + 0][j] = v.x; L[i4 + 1][j] = v.y;
            L[i4 + 2][j] = v.z; L[i4 + 3][j] = v.w;
        }
        __syncthreads();
#pragma unroll
        for (int t = 0; t < 4; ++t) {
            int n = c0 + jj + t * 16;
            int k = r0 + i4;
            ushort4 o;
            o.x = f2bf(L[jj + t * 16][i4 + 0]); o.y = f2bf(L[jj + t * 16][i4 + 1]);
            o.z = f2bf(L[jj + t * 16][i4 + 2]); o.w = f2bf(L[jj + t * 16][i4 + 3]);
            int nt = n >> 7, r = n & 127, kc = k >> 5, cc = k & 31;
            int p = (cc >> 3) ^ ((r >> 1) & 3);
            *(ushort4*)&out[(((size_t)nt * 32 + kc) << 12) + (r << 5) + p * 8 + (cc & 7)] = o;
        }
    } else {
        int idx = (bid - 5120) * 256 + tid;       // < B*MEM*C = 524288
        float val = ext[idx];
        int c = idx & (C_ - 1), m = (idx >> 10) & (MEM_ - 1), b = idx >> 18;
        int h = c >> 6, d = c & 63;
        int bh = b * H_ + h;
        unsigned short bv = f2bf(val);
        k_ws[(size_t)bh * S_ * 64 + (size_t)m * 64 + (((d >> 3) ^ (m & 7)) << 3) + (d & 7)] = bv;
        int ts = m >> 6, key = m & 63;
        v_tl[(((size_t)bh * NKT_ + ts) * 64 + d) * 64 + (((key >> 3) ^ (d & 7)) << 3) + (key & 7)] = bv;
    }
}

// ---------------------------------------------------------------------------
// bf16 MFMA GEMM on tile-major pre-swizzled inputs, async global_load_lds,
// double-buffered LDS, 1 barrier/k-chunk. 128x128 tile, BK=32, 4 waves.
// MODE 0: QKV epilogue (q natural, k row-swizzled, v tile-major swizzled).
// MODE 1: proj, fp32 out.
// ---------------------------------------------------------------------------
template<int MODE>
__global__ __launch_bounds__(256) void gemm_mfma(
    const unsigned short* __restrict__ A,     // [MT][32][128][32]
    const unsigned short* __restrict__ Bt,    // [NT][32][128][32]
    const float* __restrict__ bias,
    unsigned short* __restrict__ q_ws,
    unsigned short* __restrict__ k_ws,
    unsigned short* __restrict__ v_tl,
    float* __restrict__ out)
{
    __shared__ __align__(16) unsigned short As[2][4096];
    __shared__ __align__(16) unsigned short Bs[2][4096];
    const int tid = threadIdx.x, lane = tid & 63, wave = tid >> 6;
    const int wr = wave >> 1, wc = wave & 1;
    const size_t abase = (size_t)blockIdx.y * 32 * 4096;
    const size_t bbase = (size_t)blockIdx.x * 32 * 4096;

    f32x4 acc[4][4];
#pragma unroll
    for (int i = 0; i < 4; ++i)
#pragma unroll
        for (int j = 0; j < 4; ++j) acc[i][j] = (f32x4){0.f, 0.f, 0.f, 0.f};

    auto stage = [&](int kc, int buf) {
        const unsigned short* ga = A + abase + (size_t)kc * 4096;
        const unsigned short* gb = Bt + bbase + (size_t)kc * 4096;
#pragma unroll
        for (int s = 0; s < 2; ++s) {
            int seg = wave + s * 4;                       // 0..7
            gll16(ga + seg * 512 + lane * 8, &As[buf][seg * 512]);
            gll16(gb + seg * 512 + lane * 8, &Bs[buf][seg * 512]);
        }
    };

    stage(0, 0);
    __syncthreads();
    for (int kc = 0; kc < 32; ++kc) {
        if (kc + 1 < 32) stage(kc + 1, (kc + 1) & 1);
        const unsigned short* as = As[kc & 1];
        const unsigned short* bs = Bs[kc & 1];
        short8 af[4], bf4[4];
#pragma unroll
        for (int i = 0; i < 4; ++i) {
            int row = wr * 64 + i * 16 + (lane & 15);
            int ph = (lane >> 4) ^ ((row >> 1) & 3);
            af[i] = *(const short8*)&as[row * 32 + ph * 8];
        }
#pragma unroll
        for (int j = 0; j < 4; ++j) {
            int row = wc * 64 + j * 16 + (lane & 15);
            int ph = (lane >> 4) ^ ((row >> 1) & 3);
            bf4[j] = *(const short8*)&bs[row * 32 + ph * 8];
        }
#pragma unroll
        for (int i = 0; i < 4; ++i)
#pragma unroll
            for (int j = 0; j < 4; ++j)
                acc[i][j] = __builtin_amdgcn_mfma_f32_16x16x32_bf16(
                    af[i], bf4[j], acc[i][j], 0, 0, 0);
        __syncthreads();
    }

    if (MODE == 0) {
#pragma unroll
        for (int j = 0; j < 4; ++j) {
            int n = blockIdx.x * 128 + wc * 64 + j * 16 + (lane & 15);
            float bs = bias[n];
            int sel = n >> 10, h = (n >> 6) & 15, d = n & 63;
#pragma unroll
            for (int i = 0; i < 4; ++i) {
                int m = blockIdx.y * 128 + wr * 64 + i * 16 + (lane >> 4) * 4;
                int b = m >> 11, t0 = m & (T_ - 1);
                int bh = b * H_ + h;
                if (sel == 0) {
                    size_t base = ((size_t)bh * T_ + t0) * 64 + d;
#pragma unroll
                    for (int r = 0; r < 4; ++r)
                        q_ws[base + (size_t)r * 64] = f2bf(acc[i][j][r] + bs);
                } else if (sel == 1) {
#pragma unroll
                    for (int r = 0; r < 4; ++r) {
                        int s = MEM_ + t0 + r;
                        k_ws[(size_t)bh * S_ * 64 + (size_t)s * 64
                             + (((d >> 3) ^ (s & 7)) << 3) + (d & 7)] =
                            f2bf(acc[i][j][r] + bs);
                    }
                } else {
                    int s0 = MEM_ + t0, ts = s0 >> 6, key = s0 & 63;
                    ushort4 pv;
                    pv.x = f2bf(acc[i][j][0] + bs);
                    pv.y = f2bf(acc[i][j][1] + bs);
                    pv.z = f2bf(acc[i][j][2] + bs);
                    pv.w = f2bf(acc[i][j][3] + bs);
                    *(ushort4*)&v_tl[(((size_t)bh * NKT_ + ts) * 64 + d) * 64
                                     + (((key >> 3) ^ (d & 7)) << 3) + (key & 7)] = pv;
                }
            }
        }
    } else {
#pragma unroll
        for (int j = 0; j < 4; ++j) {
            int n = blockIdx.x * 128 + wc * 64 + j * 16 + (lane & 15);
            float bs = bias[n];
#pragma unroll
            for (int i = 0; i < 4; ++i) {
                int m = blockIdx.y * 128 + wr * 64 + i * 16 + (lane >> 4) * 4;
#pragma unroll
                for (int r = 0; r < 4; ++r)
                    out[(size_t)(m + r) * C_ + n] = acc[i][j][r] + bs;
            }
        }
    }
}

// ---------------------------------------------------------------------------
// Flash attention v5: S^T scheme + 8-wave blocks. Block = q-tile pair
// (a, 31-a) of one (b,h); waves 0-3 own tile a (16 rows each), waves 4-7 own
// tile 31-a. K/V staged ONCE per k-tile (shared by both halves); 2 blocks/CU
// -> 4 waves/SIMD (2x R4 overlap). Idle A-waves skip frag reads entirely.
// Fixed-max softmax; async dbuf staging; 1 barrier/tile.
// ---------------------------------------------------------------------------
__global__ __launch_bounds__(512) void flash_mfma(
    const unsigned short* __restrict__ qg,    // [bh][t][64] natural
    const unsigned short* __restrict__ kg,    // [bh][s][64] row-swizzled
    const unsigned short* __restrict__ vg,    // [bh][36][64][64] key-swizzled
    unsigned short* __restrict__ yt)          // proj-tiled [mt][kc][128][32]
{
    __shared__ __align__(16) unsigned short Ks[2][4096];
    __shared__ __align__(16) unsigned short Vs[2][4096];

    const int tid = threadIdx.x, lane = tid & 63, wave = tid >> 6;  // 0..7
    const int half = wave >> 2, wq = wave & 3;
    const int quad = lane >> 4;
    const int a = blockIdx.x;                  // 0..15
    const int h = blockIdx.y, b = blockIdx.z;
    const int qt = half ? (31 - a) : a;
    const int nt = 5 + qt;                     // this half's k-tile count
    const int ntMax = 36 - a;                  // loop bound (B half's count)
    const int bh = b * H_ + h;
    const size_t kbase = (size_t)bh * S_ * 64;
    const size_t vbase = (size_t)bh * NKT_ * 4096;

    // Q fragment (B-operand layout: q = lane&15, d = quad*8 + hf*32 + j)
    short8 qf[2];
    {
        const unsigned short* p = qg + ((size_t)bh * T_ + qt * 64 + wq * 16
                                        + (lane & 15)) * 64 + quad * 8;
        qf[0] = *(const short8*)p; qf[1] = *(const short8*)(p + 32);
    }

    f32x4 o[4];
#pragma unroll
    for (int j = 0; j < 4; ++j) o[j] = (f32x4){0.f, 0.f, 0.f, 0.f};
    float l = 0.f;   // per-lane partial denom for q = lane&15

    auto stage = [&](int kt, int buf) {
        const unsigned short* gk = kg + kbase + (size_t)kt * 4096;
        const unsigned short* gv = vg + vbase + (size_t)kt * 4096;
        gll16(gk + wave * 512 + lane * 8, &Ks[buf][wave * 512]);
        gll16(gv + wave * 512 + lane * 8, &Vs[buf][wave * 512]);
    };

    const float C1 = 0.18033688011112042f;     // log2(e)/sqrt(64)
    const int tq = qt * 64 + wq * 16 + (lane & 15);   // this lane's query row

    stage(0, 0);
    __syncthreads();
    for (int kt = 0; kt < ntMax; ++kt) {
        const int buf = kt & 1;
        if (kt + 1 < ntMax) stage(kt + 1, buf ^ 1);
        if (kt < nt) {
            const unsigned short* ks = Ks[buf];
            const unsigned short* vs = Vs[buf];
            const int s0 = kt * 64;
            const bool diag = (kt == nt - 1);

            // K A-frags: key = kb*16 + (lane&15), d = ksub*32 + quad*8..+7
            short8 kA[4][2];
#pragma unroll
            for (int kb = 0; kb < 4; ++kb)
#pragma unroll
                for (int ksub = 0; ksub < 2; ++ksub) {
                    int key = kb * 16 + (lane & 15);
                    int ph = (ksub * 4 + quad) ^ (lane & 7);
                    kA[kb][ksub] = *(const short8*)&ks[key * 64 + ph * 8];
                }
            // V B-frags (16x16x16): d = dblk*16+(lane&15), key = kb*16+quad*4..+3
            short4v vB[4][4];
#pragma unroll
            for (int kb = 0; kb < 4; ++kb)
#pragma unroll
                for (int dblk = 0; dblk < 4; ++dblk) {
                    int d = dblk * 16 + (lane & 15);
                    int ph = (kb * 2 + (lane >> 5)) ^ (d & 7);
                    vB[kb][dblk] = *(const short4v*)&vs[d * 64 + ph * 8 + (quad & 1) * 4];
                }

#pragma unroll
            for (int kb = 0; kb < 4; ++kb) {
                f32x4 z = (f32x4){0.f, 0.f, 0.f, 0.f};
                z = __builtin_amdgcn_mfma_f32_16x16x32_bf16(kA[kb][0], qf[0], z, 0, 0, 0);
                z = __builtin_amdgcn_mfma_f32_16x16x32_bf16(kA[kb][1], qf[1], z, 0, 0, 0);
                float p[4];
#pragma unroll
                for (int r = 0; r < 4; ++r) {
                    float e = exp2f(z[r] * C1);
                    if (diag) {
                        int key = s0 + kb * 16 + quad * 4 + r;
                        if (key - MEM_ > tq) e = 0.f;
                    }
                    l += e;
                    p[r] = e;
                }
                unsigned int r01 = pk2bf(p[0], p[1]);
                unsigned int r23 = pk2bf(p[2], p[3]);
                short4v pf;
                *(unsigned int*)&pf = r01;
                *((unsigned int*)&pf + 1) = r23;
#pragma unroll
                for (int dblk = 0; dblk < 4; ++dblk)
                    o[dblk] = __builtin_amdgcn_mfma_f32_16x16x16bf16_1k(
                        pf, vB[kb][dblk], o[dblk], 0, 0, 0);
            }
        }
        __syncthreads();   // drains prefetch + frees cur buf
    }

    // epilogue: reduce l across the 4 lane-groups, write y proj-tiled.
    l += __shfl_xor(l, 16);
    l += __shfl_xor(l, 32);
    float linv[4];
#pragma unroll
    for (int r = 0; r < 4; ++r)
        linv[r] = 1.f / __shfl(l, quad * 4 + r);
#pragma unroll
    for (int dblk = 0; dblk < 4; ++dblk) {
        int c = h * 64 + dblk * 16 + (lane & 15);
        int kc = c >> 5, cc = c & 31;
#pragma unroll
        for (int r = 0; r < 4; ++r) {
            int t = qt * 64 + wq * 16 + quad * 4 + r;
            int m = b * T_ + t;
            int mt = m >> 7, rr = m & 127;
            int p = (cc >> 3) ^ ((rr >> 1) & 3);
            yt[(((size_t)mt * 32 + kc) << 12) + (rr << 5) + p * 8 + (cc & 7)] =
                f2bf(o[dblk][r] * linv[r]);
        }
    }
}

extern "C" void kernel_launch(void* const* d_in, const int* in_sizes, int n_in,
                              void* d_out, int out_size, void* d_ws, size_t ws_size,
                              hipStream_t stream) {
    (void)in_sizes; (void)n_in; (void)out_size; (void)ws_size;
    const float* x      = (const float*)d_in[0];
    const float* ext    = (const float*)d_in[1];
    const float* W_attn = (const float*)d_in[2];
    const float* b_attn = (const float*)d_in[3];
    const float* W_proj = (const float*)d_in[4];
    const float* b_proj = (const float*)d_in[5];
    float* out = (float*)d_out;

    unsigned short* x_tl  = (unsigned short*)d_ws;           // [32][32][128][32]
    unsigned short* WtA   = x_tl + 4194304;                  // [24][32][128][32]
    unsigned short* WtP   = WtA + 3145728;                   // [8][32][128][32]
    unsigned short* q_ws  = WtP + 1048576;                   // [bh][t][64]
    unsigned short* k_ws  = q_ws + 4194304;                  // [bh][s][64] swz
    unsigned short* v_tl  = k_ws + 4718592;                  // [bh][36][64][64] swz
    unsigned short* y_tl  = v_tl + 4718592;                  // [32][32][128][32]

    dim3 blk(256);
    prep_all<<<7168, blk, 0, stream>>>(x, W_attn, W_proj, ext,
                                       x_tl, WtA, WtP, k_ws, v_tl);
    gemm_mfma<0><<<dim3(24, 32), blk, 0, stream>>>(
        x_tl, WtA, b_attn, q_ws, k_ws, v_tl, nullptr);
    flash_mfma<<<dim3(16, H_, B_), dim3(512), 0, stream>>>(q_ws, k_ws, v_tl, y_tl);
    gemm_mfma<1><<<dim3(8, 32), blk, 0, stream>>>(
        y_tl, WtP, b_proj, nullptr, nullptr, nullptr, out);
}

// Round 7
// 208.343 us; speedup vs baseline: 1.0407x; 1.0407x over previous
//
#include <hip/hip_runtime.h>

#define B_    2
#define T_    2048
#define C_    1024
#define H_    16
#define HD_   64
#define MEM_  256
#define S_    2304   // MEM + T
#define NKT_  36     // S_/64 k-tiles

typedef __attribute__((ext_vector_type(8))) short short8;   // 8 bf16 = 4 VGPRs
typedef __attribute__((ext_vector_type(4))) short short4v;  // 4 bf16 = 2 VGPRs
typedef __attribute__((ext_vector_type(4))) float f32x4;

// round-half-up bf16 (2 VALU ops; tie behavior irrelevant here)
__device__ __forceinline__ unsigned short f2bf(float x) {
    return (unsigned short)((__float_as_uint(x) + 0x8000u) >> 16);
}

// pack 2 floats -> 2 bf16 in one VGPR (round-half-up): 2 adds + 1 v_perm
__device__ __forceinline__ unsigned int pk2bf(float lo, float hi) {
    unsigned int a = __float_as_uint(lo) + 0x8000u;
    unsigned int b = __float_as_uint(hi) + 0x8000u;
    return __builtin_amdgcn_perm(b, a, 0x07060302);  // {b.hi16, a.hi16}
}

typedef const __attribute__((address_space(1))) unsigned int* gp_t;
typedef __attribute__((address_space(3))) unsigned int* lp_t;

// async global->LDS, 16B/lane. g per-lane (base + lane*8 ushorts), l wave-uniform.
__device__ __forceinline__ void gll16(const unsigned short* g, unsigned short* l) {
    __builtin_amdgcn_global_load_lds((gp_t)g, (lp_t)l, 16, 0, 0);
}

// ---------------------------------------------------------------------------
// Merged prep: job by flat blockIdx.
//  [0,4096)       convert x  -> x_tl  tile-major swizzled [mt][kc][128][32]
//  [4096,4864)    transpose W_attn -> WtA [nt][kc][128][32]
//  [4864,5120)    transpose W_proj -> WtP
//  [5120,7168)    ext_mem -> k_ws rows 0..MEM (row-swz), v_tl tiles 0..3 (swz)
// ---------------------------------------------------------------------------
__global__ __launch_bounds__(256) void prep_all(
    const float* __restrict__ x, const float* __restrict__ Wa,
    const float* __restrict__ Wp, const float* __restrict__ ext,
    unsigned short* __restrict__ x_tl, unsigned short* __restrict__ WtA,
    unsigned short* __restrict__ WtP, unsigned short* __restrict__ k_ws,
    unsigned short* __restrict__ v_tl)
{
    __shared__ float L[64][65];
    const int bid = blockIdx.x, tid = threadIdx.x;
    if (bid < 4096) {
        int i = bid * 256 + tid;                  // over 1,048,576 float4
        int c = (i & 255) * 4;
        int m = i >> 8;
        float4 v = ((const float4*)x)[i];
        ushort4 o;
        o.x = f2bf(v.x); o.y = f2bf(v.y); o.z = f2bf(v.z); o.w = f2bf(v.w);
        int mt = m >> 7, r = m & 127, kc = c >> 5, cc = c & 31;
        int p = (cc >> 3) ^ ((r >> 1) & 3);
        *(ushort4*)&x_tl[(((size_t)mt * 32 + kc) << 12) + (r << 5) + p * 8 + (cc & 7)] = o;
    } else if (bid < 5120) {
        const float* in; unsigned short* out; int Cc, r0, c0;
        if (bid < 4864) {
            int r = bid - 4096; in = Wa; out = WtA; Cc = 3 * C_;
            c0 = (r % 48) * 64; r0 = (r / 48) * 64;
        } else {
            int r = bid - 4864; in = Wp; out = WtP; Cc = C_;
            c0 = (r & 15) * 64; r0 = (r >> 4) * 64;
        }
        const int jj = tid >> 4;
        const int i4 = (tid & 15) * 4;
#pragma unroll
        for (int t = 0; t < 4; ++t) {
            int j = jj + t * 16;
            float4 v = *(const float4*)(in + (size_t)(r0 + j) * Cc + c0 + i4);
            L[i4 + 0][j] = v.x; L[i4 + 1][j] = v.y;
            L[i4 + 2][j] = v.z; L[i4 + 3][j] = v.w;
        }
        __syncthreads();
#pragma unroll
        for (int t = 0; t < 4; ++t) {
            int n = c0 + jj + t * 16;
            int k = r0 + i4;
            ushort4 o;
            o.x = f2bf(L[jj + t * 16][i4 + 0]); o.y = f2bf(L[jj + t * 16][i4 + 1]);
            o.z = f2bf(L[jj + t * 16][i4 + 2]); o.w = f2bf(L[jj + t * 16][i4 + 3]);
            int nt = n >> 7, r = n & 127, kc = k >> 5, cc = k & 31;
            int p = (cc >> 3) ^ ((r >> 1) & 3);
            *(ushort4*)&out[(((size_t)nt * 32 + kc) << 12) + (r << 5) + p * 8 + (cc & 7)] = o;
        }
    } else {
        int idx = (bid - 5120) * 256 + tid;       // < B*MEM*C = 524288
        float val = ext[idx];
        int c = idx & (C_ - 1), m = (idx >> 10) & (MEM_ - 1), b = idx >> 18;
        int h = c >> 6, d = c & 63;
        int bh = b * H_ + h;
        unsigned short bv = f2bf(val);
        k_ws[(size_t)bh * S_ * 64 + (size_t)m * 64 + (((d >> 3) ^ (m & 7)) << 3) + (d & 7)] = bv;
        int ts = m >> 6, key = m & 63;
        v_tl[(((size_t)bh * NKT_ + ts) * 64 + d) * 64 + (((key >> 3) ^ (d & 7)) << 3) + (key & 7)] = bv;
    }
}

// ---------------------------------------------------------------------------
// QKV GEMM: bf16 MFMA on tile-major pre-swizzled inputs, async
// global_load_lds, double-buffered LDS, 1 barrier/k-chunk. 128x128 tile,
// BK=32, 4 waves. Epilogue scatters q natural, k row-swizzled, v tile-major.
// ---------------------------------------------------------------------------
__global__ __launch_bounds__(256) void qkv_gemm(
    const unsigned short* __restrict__ A,     // [32][32][128][32]
    const unsigned short* __restrict__ Bt,    // [24][32][128][32]
    const float* __restrict__ bias,
    unsigned short* __restrict__ q_ws,
    unsigned short* __restrict__ k_ws,
    unsigned short* __restrict__ v_tl)
{
    __shared__ __align__(16) unsigned short As[2][4096];
    __shared__ __align__(16) unsigned short Bs[2][4096];
    const int tid = threadIdx.x, lane = tid & 63, wave = tid >> 6;
    const int wr = wave >> 1, wc = wave & 1;
    const size_t abase = (size_t)blockIdx.y * 32 * 4096;
    const size_t bbase = (size_t)blockIdx.x * 32 * 4096;

    f32x4 acc[4][4];
#pragma unroll
    for (int i = 0; i < 4; ++i)
#pragma unroll
        for (int j = 0; j < 4; ++j) acc[i][j] = (f32x4){0.f, 0.f, 0.f, 0.f};

    auto stage = [&](int kc, int buf) {
        const unsigned short* ga = A + abase + (size_t)kc * 4096;
        const unsigned short* gb = Bt + bbase + (size_t)kc * 4096;
#pragma unroll
        for (int s = 0; s < 2; ++s) {
            int seg = wave + s * 4;                       // 0..7
            gll16(ga + seg * 512 + lane * 8, &As[buf][seg * 512]);
            gll16(gb + seg * 512 + lane * 8, &Bs[buf][seg * 512]);
        }
    };

    stage(0, 0);
    __syncthreads();
    for (int kc = 0; kc < 32; ++kc) {
        if (kc + 1 < 32) stage(kc + 1, (kc + 1) & 1);
        const unsigned short* as = As[kc & 1];
        const unsigned short* bs = Bs[kc & 1];
        short8 af[4], bf4[4];
#pragma unroll
        for (int i = 0; i < 4; ++i) {
            int row = wr * 64 + i * 16 + (lane & 15);
            int ph = (lane >> 4) ^ ((row >> 1) & 3);
            af[i] = *(const short8*)&as[row * 32 + ph * 8];
        }
#pragma unroll
        for (int j = 0; j < 4; ++j) {
            int row = wc * 64 + j * 16 + (lane & 15);
            int ph = (lane >> 4) ^ ((row >> 1) & 3);
            bf4[j] = *(const short8*)&bs[row * 32 + ph * 8];
        }
#pragma unroll
        for (int i = 0; i < 4; ++i)
#pragma unroll
            for (int j = 0; j < 4; ++j)
                acc[i][j] = __builtin_amdgcn_mfma_f32_16x16x32_bf16(
                    af[i], bf4[j], acc[i][j], 0, 0, 0);
        __syncthreads();
    }

#pragma unroll
    for (int j = 0; j < 4; ++j) {
        int n = blockIdx.x * 128 + wc * 64 + j * 16 + (lane & 15);
        float bs = bias[n];
        int sel = n >> 10, h = (n >> 6) & 15, d = n & 63;
#pragma unroll
        for (int i = 0; i < 4; ++i) {
            int m = blockIdx.y * 128 + wr * 64 + i * 16 + (lane >> 4) * 4;
            int b = m >> 11, t0 = m & (T_ - 1);
            int bh = b * H_ + h;
            if (sel == 0) {
                size_t base = ((size_t)bh * T_ + t0) * 64 + d;
#pragma unroll
                for (int r = 0; r < 4; ++r)
                    q_ws[base + (size_t)r * 64] = f2bf(acc[i][j][r] + bs);
            } else if (sel == 1) {
#pragma unroll
                for (int r = 0; r < 4; ++r) {
                    int s = MEM_ + t0 + r;
                    k_ws[(size_t)bh * S_ * 64 + (size_t)s * 64
                         + (((d >> 3) ^ (s & 7)) << 3) + (d & 7)] =
                        f2bf(acc[i][j][r] + bs);
                }
            } else {
                int s0 = MEM_ + t0, ts = s0 >> 6, key = s0 & 63;
                ushort4 pv;
                pv.x = f2bf(acc[i][j][0] + bs);
                pv.y = f2bf(acc[i][j][1] + bs);
                pv.z = f2bf(acc[i][j][2] + bs);
                pv.w = f2bf(acc[i][j][3] + bs);
                *(ushort4*)&v_tl[(((size_t)bh * NKT_ + ts) * 64 + d) * 64
                                 + (((key >> 3) ^ (d & 7)) << 3) + (key & 7)] = pv;
            }
        }
    }
}

// ---------------------------------------------------------------------------
// Proj GEMM: 64x128 tiles -> 512 blocks (2/CU, 2 waves/SIMD; the old 128x128
// gave only 256 blocks = 1 wave/SIMD). 4 waves; wave w owns n-cols
// [w*32, w*32+32): 4 A-frags (shared rows) + 2 B-frags, 8 MFMA/chunk.
// ---------------------------------------------------------------------------
__global__ __launch_bounds__(256) void proj_gemm(
    const unsigned short* __restrict__ A,     // y_tl [32][32][128][32]
    const unsigned short* __restrict__ Bt,    // WtP  [8][32][128][32]
    const float* __restrict__ bias,
    float* __restrict__ out)
{
    __shared__ __align__(16) unsigned short As[2][2048];
    __shared__ __align__(16) unsigned short Bs[2][4096];
    const int tid = threadIdx.x, lane = tid & 63, wave = tid >> 6;
    const int m64 = blockIdx.y;               // 0..63
    const size_t abase = ((size_t)(m64 >> 1) * 32) * 4096 + (size_t)(m64 & 1) * 2048;
    const size_t bbase = (size_t)blockIdx.x * 32 * 4096;

    f32x4 acc[4][2];
#pragma unroll
    for (int i = 0; i < 4; ++i)
#pragma unroll
        for (int j = 0; j < 2; ++j) acc[i][j] = (f32x4){0.f, 0.f, 0.f, 0.f};

    auto stage = [&](int kc, int buf) {
        const unsigned short* ga = A + abase + (size_t)kc * 4096;
        const unsigned short* gb = Bt + bbase + (size_t)kc * 4096;
        gll16(ga + wave * 512 + lane * 8, &As[buf][wave * 512]);
        gll16(gb + wave * 512 + lane * 8, &Bs[buf][wave * 512]);
        gll16(gb + (wave + 4) * 512 + lane * 8, &Bs[buf][(wave + 4) * 512]);
    };

    stage(0, 0);
    __syncthreads();
    for (int kc = 0; kc < 32; ++kc) {
        if (kc + 1 < 32) stage(kc + 1, (kc + 1) & 1);
        const unsigned short* as = As[kc & 1];
        const unsigned short* bs = Bs[kc & 1];
        short8 af[4], bf2[2];
#pragma unroll
        for (int i = 0; i < 4; ++i) {
            int row = i * 16 + (lane & 15);           // local row in 64-tile
            int ph = (lane >> 4) ^ ((row >> 1) & 3);  // (64+row) swizzle == row swizzle
            af[i] = *(const short8*)&as[row * 32 + ph * 8];
        }
#pragma unroll
        for (int j = 0; j < 2; ++j) {
            int row = wave * 32 + j * 16 + (lane & 15);
            int ph = (lane >> 4) ^ ((row >> 1) & 3);
            bf2[j] = *(const short8*)&bs[row * 32 + ph * 8];
        }
#pragma unroll
        for (int i = 0; i < 4; ++i)
#pragma unroll
            for (int j = 0; j < 2; ++j)
                acc[i][j] = __builtin_amdgcn_mfma_f32_16x16x32_bf16(
                    af[i], bf2[j], acc[i][j], 0, 0, 0);
        __syncthreads();
    }

#pragma unroll
    for (int j = 0; j < 2; ++j) {
        int n = blockIdx.x * 128 + wave * 32 + j * 16 + (lane & 15);
        float bs = bias[n];
#pragma unroll
        for (int i = 0; i < 4; ++i) {
            int m = m64 * 64 + i * 16 + (lane >> 4) * 4;
#pragma unroll
            for (int r = 0; r < 4; ++r)
                out[(size_t)(m + r) * C_ + n] = acc[i][j][r] + bs;
        }
    }
}

// ---------------------------------------------------------------------------
// Flash attention v6: 8-wave blocks with __launch_bounds__(512,4) so the
// compiler keeps ~110 VGPRs (R5's default bounds minimized to 36 -> spills).
// Block = q-tile pair (a, 31-a); waves 0-3 own tile a, waves 4-7 tile 31-a.
// K/V staged once per k-tile, shared. S^T scheme: P^T C-layout == A-operand
// layout, no LDS round-trip. Fixed-max softmax. Async dbuf, 1 barrier/tile.
// ---------------------------------------------------------------------------
__global__ __launch_bounds__(512, 4) void flash_mfma(
    const unsigned short* __restrict__ qg,    // [bh][t][64] natural
    const unsigned short* __restrict__ kg,    // [bh][s][64] row-swizzled
    const unsigned short* __restrict__ vg,    // [bh][36][64][64] key-swizzled
    unsigned short* __restrict__ yt)          // proj-tiled [mt][kc][128][32]
{
    __shared__ __align__(16) unsigned short Ks[2][4096];
    __shared__ __align__(16) unsigned short Vs[2][4096];

    const int tid = threadIdx.x, lane = tid & 63, wave = tid >> 6;  // 0..7
    const int half = wave >> 2, wq = wave & 3;
    const int quad = lane >> 4;
    const int a = blockIdx.x;                  // 0..15
    const int h = blockIdx.y, b = blockIdx.z;
    const int qt = half ? (31 - a) : a;
    const int nt = 5 + qt;                     // this half's k-tile count
    const int ntMax = 36 - a;                  // loop bound (B half's count)
    const int bh = b * H_ + h;
    const size_t kbase = (size_t)bh * S_ * 64;
    const size_t vbase = (size_t)bh * NKT_ * 4096;

    // Q fragment (B-operand layout: q = lane&15, d = quad*8 + hf*32 + j)
    short8 qf[2];
    {
        const unsigned short* p = qg + ((size_t)bh * T_ + qt * 64 + wq * 16
                                        + (lane & 15)) * 64 + quad * 8;
        qf[0] = *(const short8*)p; qf[1] = *(const short8*)(p + 32);
    }

    f32x4 o[4];
#pragma unroll
    for (int j = 0; j < 4; ++j) o[j] = (f32x4){0.f, 0.f, 0.f, 0.f};
    float l = 0.f;   // per-lane partial denom for q = lane&15

    auto stage = [&](int kt, int buf) {
        const unsigned short* gk = kg + kbase + (size_t)kt * 4096;
        const unsigned short* gv = vg + vbase + (size_t)kt * 4096;
        gll16(gk + wave * 512 + lane * 8, &Ks[buf][wave * 512]);
        gll16(gv + wave * 512 + lane * 8, &Vs[buf][wave * 512]);
    };

    const float C1 = 0.18033688011112042f;     // log2(e)/sqrt(64)
    const int tq = qt * 64 + wq * 16 + (lane & 15);   // this lane's query row

    stage(0, 0);
    __syncthreads();
    for (int kt = 0; kt < ntMax; ++kt) {
        const int buf = kt & 1;
        if (kt + 1 < ntMax) stage(kt + 1, buf ^ 1);
        if (kt < nt) {
            const unsigned short* ks = Ks[buf];
            const unsigned short* vs = Vs[buf];
            const int s0 = kt * 64;
            const bool diag = (kt == nt - 1);

            // K A-frags: key = kb*16 + (lane&15), d = ksub*32 + quad*8..+7
            short8 kA[4][2];
#pragma unroll
            for (int kb = 0; kb < 4; ++kb)
#pragma unroll
                for (int ksub = 0; ksub < 2; ++ksub) {
                    int key = kb * 16 + (lane & 15);
                    int ph = (ksub * 4 + quad) ^ (lane & 7);
                    kA[kb][ksub] = *(const short8*)&ks[key * 64 + ph * 8];
                }
            // V B-frags (16x16x16): d = dblk*16+(lane&15), key = kb*16+quad*4..+3
            short4v vB[4][4];
#pragma unroll
            for (int kb = 0; kb < 4; ++kb)
#pragma unroll
                for (int dblk = 0; dblk < 4; ++dblk) {
                    int d = dblk * 16 + (lane & 15);
                    int ph = (kb * 2 + (lane >> 5)) ^ (d & 7);
                    vB[kb][dblk] = *(const short4v*)&vs[d * 64 + ph * 8 + (quad & 1) * 4];
                }

#pragma unroll
            for (int kb = 0; kb < 4; ++kb) {
                f32x4 z = (f32x4){0.f, 0.f, 0.f, 0.f};
                z = __builtin_amdgcn_mfma_f32_16x16x32_bf16(kA[kb][0], qf[0], z, 0, 0, 0);
                z = __builtin_amdgcn_mfma_f32_16x16x32_bf16(kA[kb][1], qf[1], z, 0, 0, 0);
                float p[4];
#pragma unroll
                for (int r = 0; r < 4; ++r) {
                    float e = exp2f(z[r] * C1);
                    if (diag) {
                        int key = s0 + kb * 16 + quad * 4 + r;
                        if (key - MEM_ > tq) e = 0.f;
                    }
                    l += e;
                    p[r] = e;
                }
                unsigned int r01 = pk2bf(p[0], p[1]);
                unsigned int r23 = pk2bf(p[2], p[3]);
                short4v pf;
                *(unsigned int*)&pf = r01;
                *((unsigned int*)&pf + 1) = r23;
#pragma unroll
                for (int dblk = 0; dblk < 4; ++dblk)
                    o[dblk] = __builtin_amdgcn_mfma_f32_16x16x16bf16_1k(
                        pf, vB[kb][dblk], o[dblk], 0, 0, 0);
            }
        }
        __syncthreads();   // drains prefetch + frees cur buf
    }

    // epilogue: reduce l across the 4 lane-groups, write y proj-tiled.
    l += __shfl_xor(l, 16);
    l += __shfl_xor(l, 32);
    float linv[4];
#pragma unroll
    for (int r = 0; r < 4; ++r)
        linv[r] = 1.f / __shfl(l, quad * 4 + r);
#pragma unroll
    for (int dblk = 0; dblk < 4; ++dblk) {
        int c = h * 64 + dblk * 16 + (lane & 15);
        int kc = c >> 5, cc = c & 31;
#pragma unroll
        for (int r = 0; r < 4; ++r) {
            int t = qt * 64 + wq * 16 + quad * 4 + r;
            int m = b * T_ + t;
            int mt = m >> 7, rr = m & 127;
            int p = (cc >> 3) ^ ((rr >> 1) & 3);
            yt[(((size_t)mt * 32 + kc) << 12) + (rr << 5) + p * 8 + (cc & 7)] =
                f2bf(o[dblk][r] * linv[r]);
        }
    }
}

extern "C" void kernel_launch(void* const* d_in, const int* in_sizes, int n_in,
                              void* d_out, int out_size, void* d_ws, size_t ws_size,
                              hipStream_t stream) {
    (void)in_sizes; (void)n_in; (void)out_size; (void)ws_size;
    const float* x      = (const float*)d_in[0];
    const float* ext    = (const float*)d_in[1];
    const float* W_attn = (const float*)d_in[2];
    const float* b_attn = (const float*)d_in[3];
    const float* W_proj = (const float*)d_in[4];
    const float* b_proj = (const float*)d_in[5];
    float* out = (float*)d_out;

    unsigned short* x_tl  = (unsigned short*)d_ws;           // [32][32][128][32]
    unsigned short* WtA   = x_tl + 4194304;                  // [24][32][128][32]
    unsigned short* WtP   = WtA + 3145728;                   // [8][32][128][32]
    unsigned short* q_ws  = WtP + 1048576;                   // [bh][t][64]
    unsigned short* k_ws  = q_ws + 4194304;                  // [bh][s][64] swz
    unsigned short* v_tl  = k_ws + 4718592;                  // [bh][36][64][64] swz
    unsigned short* y_tl  = v_tl + 4718592;                  // [32][32][128][32]

    dim3 blk(256);
    prep_all<<<7168, blk, 0, stream>>>(x, W_attn, W_proj, ext,
                                       x_tl, WtA, WtP, k_ws, v_tl);
    qkv_gemm<<<dim3(24, 32), blk, 0, stream>>>(
        x_tl, WtA, b_attn, q_ws, k_ws, v_tl);
    flash_mfma<<<dim3(16, H_, B_), dim3(512), 0, stream>>>(q_ws, k_ws, v_tl, y_tl);
    proj_gemm<<<dim3(8, 64), blk, 0, stream>>>(y_tl, WtP, b_proj, out);
}

// Round 10
// 207.178 us; speedup vs baseline: 1.0465x; 1.0056x over previous
//
#include <hip/hip_runtime.h>

#define B_    2
#define T_    2048
#define C_    1024
#define H_    16
#define HD_   64
#define MEM_  256
#define S_    2304   // MEM + T
#define NKT_  36     // S_/64 k-tiles

typedef __attribute__((ext_vector_type(8))) short short8;   // 8 bf16 = 4 VGPRs
typedef __attribute__((ext_vector_type(4))) short short4v;  // 4 bf16 = 2 VGPRs
typedef __attribute__((ext_vector_type(4))) float f32x4;

// round-half-up bf16 (2 VALU ops; tie behavior irrelevant here)
__device__ __forceinline__ unsigned short f2bf(float x) {
    return (unsigned short)((__float_as_uint(x) + 0x8000u) >> 16);
}

// pack 2 floats -> 2 bf16 in one VGPR (round-half-up): 2 adds + 1 v_perm
__device__ __forceinline__ unsigned int pk2bf(float lo, float hi) {
    unsigned int a = __float_as_uint(lo) + 0x8000u;
    unsigned int b = __float_as_uint(hi) + 0x8000u;
    return __builtin_amdgcn_perm(b, a, 0x07060302);  // {b.hi16, a.hi16}
}

typedef const __attribute__((address_space(1))) unsigned int* gp_t;
typedef __attribute__((address_space(3))) unsigned int* lp_t;

// async global->LDS, 16B/lane. g per-lane (base + lane*8 ushorts), l wave-uniform.
__device__ __forceinline__ void gll16(const unsigned short* g, unsigned short* l) {
    __builtin_amdgcn_global_load_lds((gp_t)g, (lp_t)l, 16, 0, 0);
}

#define C1_ 0.18033688011112042f   // log2(e)/sqrt(64), pre-folded into q

// ---------------------------------------------------------------------------
// Merged prep: job by flat blockIdx.
//  [0,4096)       convert x  -> x_tl  tile-major swizzled [mt][kc][128][32]
//  [4096,4864)    transpose W_attn -> WtA [nt][kc][128][32]
//  [4864,5120)    transpose W_proj -> WtP
//  [5120,7168)    ext_mem -> k_ws rows 0..MEM (row-swz), v_tl tiles 0..3 (swz)
// ---------------------------------------------------------------------------
__global__ __launch_bounds__(256) void prep_all(
    const float* __restrict__ x, const float* __restrict__ Wa,
    const float* __restrict__ Wp, const float* __restrict__ ext,
    unsigned short* __restrict__ x_tl, unsigned short* __restrict__ WtA,
    unsigned short* __restrict__ WtP, unsigned short* __restrict__ k_ws,
    unsigned short* __restrict__ v_tl)
{
    __shared__ float L[64][65];
    const int bid = blockIdx.x, tid = threadIdx.x;
    if (bid < 4096) {
        int i = bid * 256 + tid;                  // over 1,048,576 float4
        int c = (i & 255) * 4;
        int m = i >> 8;
        float4 v = ((const float4*)x)[i];
        ushort4 o;
        o.x = f2bf(v.x); o.y = f2bf(v.y); o.z = f2bf(v.z); o.w = f2bf(v.w);
        int mt = m >> 7, r = m & 127, kc = c >> 5, cc = c & 31;
        int p = (cc >> 3) ^ ((r >> 1) & 3);
        *(ushort4*)&x_tl[(((size_t)mt * 32 + kc) << 12) + (r << 5) + p * 8 + (cc & 7)] = o;
    } else if (bid < 5120) {
        const float* in; unsigned short* out; int Cc, r0, c0;
        if (bid < 4864) {
            int r = bid - 4096; in = Wa; out = WtA; Cc = 3 * C_;
            c0 = (r % 48) * 64; r0 = (r / 48) * 64;
        } else {
            int r = bid - 4864; in = Wp; out = WtP; Cc = C_;
            c0 = (r & 15) * 64; r0 = (r >> 4) * 64;
        }
        const int jj = tid >> 4;
        const int i4 = (tid & 15) * 4;
#pragma unroll
        for (int t = 0; t < 4; ++t) {
            int j = jj + t * 16;
            float4 v = *(const float4*)(in + (size_t)(r0 + j) * Cc + c0 + i4);
            L[i4 + 0][j] = v.x; L[i4 + 1][j] = v.y;
            L[i4 + 2][j] = v.z; L[i4 + 3][j] = v.w;
        }
        __syncthreads();
#pragma unroll
        for (int t = 0; t < 4; ++t) {
            int n = c0 + jj + t * 16;
            int k = r0 + i4;
            ushort4 o;
            o.x = f2bf(L[jj + t * 16][i4 + 0]); o.y = f2bf(L[jj + t * 16][i4 + 1]);
            o.z = f2bf(L[jj + t * 16][i4 + 2]); o.w = f2bf(L[jj + t * 16][i4 + 3]);
            int nt = n >> 7, r = n & 127, kc = k >> 5, cc = k & 31;
            int p = (cc >> 3) ^ ((r >> 1) & 3);
            *(ushort4*)&out[(((size_t)nt * 32 + kc) << 12) + (r << 5) + p * 8 + (cc & 7)] = o;
        }
    } else {
        int idx = (bid - 5120) * 256 + tid;       // < B*MEM*C = 524288
        float val = ext[idx];
        int c = idx & (C_ - 1), m = (idx >> 10) & (MEM_ - 1), b = idx >> 18;
        int h = c >> 6, d = c & 63;
        int bh = b * H_ + h;
        unsigned short bv = f2bf(val);
        k_ws[(size_t)bh * S_ * 64 + (size_t)m * 64 + (((d >> 3) ^ (m & 7)) << 3) + (d & 7)] = bv;
        int ts = m >> 6, key = m & 63;
        v_tl[(((size_t)bh * NKT_ + ts) * 64 + d) * 64 + (((key >> 3) ^ (d & 7)) << 3) + (key & 7)] = bv;
    }
}

// ---------------------------------------------------------------------------
// QKV GEMM: bf16 MFMA on tile-major pre-swizzled inputs, async
// global_load_lds, double-buffered LDS, 1 barrier/k-chunk. 128x128 tile,
// BK=32, 4 waves. Epilogue scatters q natural (PRE-SCALED by log2(e)/8 so
// flash skips the per-score multiply), k row-swizzled, v tile-major.
// ---------------------------------------------------------------------------
__global__ __launch_bounds__(256) void qkv_gemm(
    const unsigned short* __restrict__ A,     // [32][32][128][32]
    const unsigned short* __restrict__ Bt,    // [24][32][128][32]
    const float* __restrict__ bias,
    unsigned short* __restrict__ q_ws,
    unsigned short* __restrict__ k_ws,
    unsigned short* __restrict__ v_tl)
{
    __shared__ __align__(16) unsigned short As[2][4096];
    __shared__ __align__(16) unsigned short Bs[2][4096];
    const int tid = threadIdx.x, lane = tid & 63, wave = tid >> 6;
    const int wr = wave >> 1, wc = wave & 1;
    const size_t abase = (size_t)blockIdx.y * 32 * 4096;
    const size_t bbase = (size_t)blockIdx.x * 32 * 4096;

    f32x4 acc[4][4];
#pragma unroll
    for (int i = 0; i < 4; ++i)
#pragma unroll
        for (int j = 0; j < 4; ++j) acc[i][j] = (f32x4){0.f, 0.f, 0.f, 0.f};

    auto stage = [&](int kc, int buf) {
        const unsigned short* ga = A + abase + (size_t)kc * 4096;
        const unsigned short* gb = Bt + bbase + (size_t)kc * 4096;
#pragma unroll
        for (int s = 0; s < 2; ++s) {
            int seg = wave + s * 4;                       // 0..7
            gll16(ga + seg * 512 + lane * 8, &As[buf][seg * 512]);
            gll16(gb + seg * 512 + lane * 8, &Bs[buf][seg * 512]);
        }
    };

    stage(0, 0);
    __syncthreads();
    for (int kc = 0; kc < 32; ++kc) {
        if (kc + 1 < 32) stage(kc + 1, (kc + 1) & 1);
        const unsigned short* as = As[kc & 1];
        const unsigned short* bs = Bs[kc & 1];
        short8 af[4], bf4[4];
#pragma unroll
        for (int i = 0; i < 4; ++i) {
            int row = wr * 64 + i * 16 + (lane & 15);
            int ph = (lane >> 4) ^ ((row >> 1) & 3);
            af[i] = *(const short8*)&as[row * 32 + ph * 8];
        }
#pragma unroll
        for (int j = 0; j < 4; ++j) {
            int row = wc * 64 + j * 16 + (lane & 15);
            int ph = (lane >> 4) ^ ((row >> 1) & 3);
            bf4[j] = *(const short8*)&bs[row * 32 + ph * 8];
        }
#pragma unroll
        for (int i = 0; i < 4; ++i)
#pragma unroll
            for (int j = 0; j < 4; ++j)
                acc[i][j] = __builtin_amdgcn_mfma_f32_16x16x32_bf16(
                    af[i], bf4[j], acc[i][j], 0, 0, 0);
        __syncthreads();
    }

#pragma unroll
    for (int j = 0; j < 4; ++j) {
        int n = blockIdx.x * 128 + wc * 64 + j * 16 + (lane & 15);
        float bs = bias[n];
        int sel = n >> 10, h = (n >> 6) & 15, d = n & 63;
#pragma unroll
        for (int i = 0; i < 4; ++i) {
            int m = blockIdx.y * 128 + wr * 64 + i * 16 + (lane >> 4) * 4;
            int b = m >> 11, t0 = m & (T_ - 1);
            int bh = b * H_ + h;
            if (sel == 0) {
                size_t base = ((size_t)bh * T_ + t0) * 64 + d;
#pragma unroll
                for (int r = 0; r < 4; ++r)
                    q_ws[base + (size_t)r * 64] = f2bf((acc[i][j][r] + bs) * C1_);
            } else if (sel == 1) {
#pragma unroll
                for (int r = 0; r < 4; ++r) {
                    int s = MEM_ + t0 + r;
                    k_ws[(size_t)bh * S_ * 64 + (size_t)s * 64
                         + (((d >> 3) ^ (s & 7)) << 3) + (d & 7)] =
                        f2bf(acc[i][j][r] + bs);
                }
            } else {
                int s0 = MEM_ + t0, ts = s0 >> 6, key = s0 & 63;
                ushort4 pv;
                pv.x = f2bf(acc[i][j][0] + bs);
                pv.y = f2bf(acc[i][j][1] + bs);
                pv.z = f2bf(acc[i][j][2] + bs);
                pv.w = f2bf(acc[i][j][3] + bs);
                *(ushort4*)&v_tl[(((size_t)bh * NKT_ + ts) * 64 + d) * 64
                                 + (((key >> 3) ^ (d & 7)) << 3) + (key & 7)] = pv;
            }
        }
    }
}

// ---------------------------------------------------------------------------
// Proj GEMM: 64x128 tiles -> 512 blocks (2/CU, 2 waves/SIMD). 4 waves; wave w
// owns n-cols [w*32, w*32+32): 4 A-frags + 2 B-frags, 8 MFMA/chunk.
// ---------------------------------------------------------------------------
__global__ __launch_bounds__(256) void proj_gemm(
    const unsigned short* __restrict__ A,     // y_tl [32][32][128][32]
    const unsigned short* __restrict__ Bt,    // WtP  [8][32][128][32]
    const float* __restrict__ bias,
    float* __restrict__ out)
{
    __shared__ __align__(16) unsigned short As[2][2048];
    __shared__ __align__(16) unsigned short Bs[2][4096];
    const int tid = threadIdx.x, lane = tid & 63, wave = tid >> 6;
    const int m64 = blockIdx.y;               // 0..63
    const size_t abase = ((size_t)(m64 >> 1) * 32) * 4096 + (size_t)(m64 & 1) * 2048;
    const size_t bbase = (size_t)blockIdx.x * 32 * 4096;

    f32x4 acc[4][2];
#pragma unroll
    for (int i = 0; i < 4; ++i)
#pragma unroll
        for (int j = 0; j < 2; ++j) acc[i][j] = (f32x4){0.f, 0.f, 0.f, 0.f};

    auto stage = [&](int kc, int buf) {
        const unsigned short* ga = A + abase + (size_t)kc * 4096;
        const unsigned short* gb = Bt + bbase + (size_t)kc * 4096;
        gll16(ga + wave * 512 + lane * 8, &As[buf][wave * 512]);
        gll16(gb + wave * 512 + lane * 8, &Bs[buf][wave * 512]);
        gll16(gb + (wave + 4) * 512 + lane * 8, &Bs[buf][(wave + 4) * 512]);
    };

    stage(0, 0);
    __syncthreads();
    for (int kc = 0; kc < 32; ++kc) {
        if (kc + 1 < 32) stage(kc + 1, (kc + 1) & 1);
        const unsigned short* as = As[kc & 1];
        const unsigned short* bs = Bs[kc & 1];
        short8 af[4], bf2[2];
#pragma unroll
        for (int i = 0; i < 4; ++i) {
            int row = i * 16 + (lane & 15);           // local row in 64-tile
            int ph = (lane >> 4) ^ ((row >> 1) & 3);  // (64+row) swizzle == row swizzle
            af[i] = *(const short8*)&as[row * 32 + ph * 8];
        }
#pragma unroll
        for (int j = 0; j < 2; ++j) {
            int row = wave * 32 + j * 16 + (lane & 15);
            int ph = (lane >> 4) ^ ((row >> 1) & 3);
            bf2[j] = *(const short8*)&bs[row * 32 + ph * 8];
        }
#pragma unroll
        for (int i = 0; i < 4; ++i)
#pragma unroll
            for (int j = 0; j < 2; ++j)
                acc[i][j] = __builtin_amdgcn_mfma_f32_16x16x32_bf16(
                    af[i], bf2[j], acc[i][j], 0, 0, 0);
        __syncthreads();
    }

#pragma unroll
    for (int j = 0; j < 2; ++j) {
        int n = blockIdx.x * 128 + wave * 32 + j * 16 + (lane & 15);
        float bs = bias[n];
#pragma unroll
        for (int i = 0; i < 4; ++i) {
            int m = m64 * 64 + i * 16 + (lane >> 4) * 4;
#pragma unroll
            for (int r = 0; r < 4; ++r)
                out[(size_t)(m + r) * C_ + n] = acc[i][j][r] + bs;
        }
    }
}

// ---------------------------------------------------------------------------
// Flash attention v7b: R8's address-VALU elimination (loop-invariant LDS base
// pointers + pre-scaled Q) with R7's proven canonical loop shape (single for,
// uniform B = (kt&1)<<12; 6 uniform VGPR adds/tile, negligible).
// 8-wave blocks: waves 0-3 tile a, 4-7 tile 31-a; K/V staged once per tile.
// S^T scheme (P^T C-layout == A-operand layout, no LDS round-trip for P).
// ---------------------------------------------------------------------------
__global__ __launch_bounds__(512, 4) void flash_mfma(
    const unsigned short* __restrict__ qg,    // [bh][t][64] natural, pre-scaled
    const unsigned short* __restrict__ kg,    // [bh][s][64] row-swizzled
    const unsigned short* __restrict__ vg,    // [bh][36][64][64] key-swizzled
    unsigned short* __restrict__ yt)          // proj-tiled [mt][kc][128][32]
{
    __shared__ __align__(16) unsigned short Ks[2][4096];
    __shared__ __align__(16) unsigned short Vs[2][4096];

    const int tid = threadIdx.x, lane = tid & 63, wave = tid >> 6;  // 0..7
    const int half = wave >> 2, wq = wave & 3;
    const int quad = lane >> 4;
    const int a = blockIdx.x;                  // 0..15
    const int h = blockIdx.y, b = blockIdx.z;
    const int qt = half ? (31 - a) : a;
    const int nt = 5 + qt;                     // this half's k-tile count
    const int ntMax = 36 - a;                  // loop bound (B half's count)
    const int bh = b * H_ + h;
    const size_t kgb = (size_t)bh * S_ * 64;
    const size_t vgb = (size_t)bh * NKT_ * 4096;

    // Q fragment (B-operand layout: q = lane&15, d = quad*8 + hf*32 + j)
    short8 qf[2];
    {
        const unsigned short* p = qg + ((size_t)bh * T_ + qt * 64 + wq * 16
                                        + (lane & 15)) * 64 + quad * 8;
        qf[0] = *(const short8*)p; qf[1] = *(const short8*)(p + 32);
    }

    f32x4 o[4];
#pragma unroll
    for (int j = 0; j < 4; ++j) o[j] = (f32x4){0.f, 0.f, 0.f, 0.f};
    float l = 0.f;   // per-lane partial denom for q = lane&15

    // Loop-invariant LDS base pointers (ushort units).
    const unsigned short* kB0 = &Ks[0][(lane & 15) * 64 + ((quad ^ (lane & 7)) * 8)];
    const unsigned short* kB1 = &Ks[0][(lane & 15) * 64 + (((quad + 4) ^ (lane & 7)) * 8)];
    const unsigned short* vPs[4];
#pragma unroll
    for (int kb = 0; kb < 4; ++kb)
        vPs[kb] = &Vs[0][(lane & 15) * 64
                         + (((kb * 2 + (lane >> 5)) ^ (lane & 7)) * 8)
                         + (quad & 1) * 4];

    auto stageTo = [&](int kt, int ofs) {     // ofs in ushorts: 0 or 4096
        const unsigned short* gk = kg + kgb + (size_t)kt * 4096;
        const unsigned short* gv = vg + vgb + (size_t)kt * 4096;
        gll16(gk + wave * 512 + lane * 8, &Ks[0][ofs + wave * 512]);
        gll16(gv + wave * 512 + lane * 8, &Vs[0][ofs + wave * 512]);
    };

    const int tq = qt * 64 + wq * 16 + (lane & 15);   // this lane's query row

    stageTo(0, 0);
    __syncthreads();
    for (int kt = 0; kt < ntMax; ++kt) {
        const int B = (kt & 1) << 12;         // current buf offset, ushorts
        if (kt + 1 < ntMax) stageTo(kt + 1, B ^ 4096);
        if (kt < nt) {
            const bool diag = (kt == nt - 1);
            const int s0 = kt * 64;
            short8 kA[4][2];
#pragma unroll
            for (int kb = 0; kb < 4; ++kb) {
                kA[kb][0] = *(const short8*)&kB0[B + kb * 1024];
                kA[kb][1] = *(const short8*)&kB1[B + kb * 1024];
            }
            short4v vF[4][4];
#pragma unroll
            for (int kb = 0; kb < 4; ++kb)
#pragma unroll
                for (int dblk = 0; dblk < 4; ++dblk)
                    vF[kb][dblk] = *(const short4v*)&vPs[kb][B + dblk * 1024];

#pragma unroll
            for (int kb = 0; kb < 4; ++kb) {
                f32x4 z = (f32x4){0.f, 0.f, 0.f, 0.f};
                z = __builtin_amdgcn_mfma_f32_16x16x32_bf16(kA[kb][0], qf[0], z, 0, 0, 0);
                z = __builtin_amdgcn_mfma_f32_16x16x32_bf16(kA[kb][1], qf[1], z, 0, 0, 0);
                float p[4];
#pragma unroll
                for (int r = 0; r < 4; ++r) {
                    float e = exp2f(z[r]);            // q pre-scaled
                    if (diag) {
                        int key = s0 + kb * 16 + quad * 4 + r;
                        if (key - MEM_ > tq) e = 0.f;
                    }
                    l += e;
                    p[r] = e;
                }
                unsigned int r01 = pk2bf(p[0], p[1]);
                unsigned int r23 = pk2bf(p[2], p[3]);
                short4v pf;
                *(unsigned int*)&pf = r01;
                *((unsigned int*)&pf + 1) = r23;
#pragma unroll
                for (int dblk = 0; dblk < 4; ++dblk)
                    o[dblk] = __builtin_amdgcn_mfma_f32_16x16x16bf16_1k(
                        pf, vF[kb][dblk], o[dblk], 0, 0, 0);
            }
        }
        __syncthreads();   // drains prefetch + frees cur buf
    }

    // epilogue: reduce l across the 4 lane-groups, write y proj-tiled.
    l += __shfl_xor(l, 16);
    l += __shfl_xor(l, 32);
    float linv[4];
#pragma unroll
    for (int r = 0; r < 4; ++r)
        linv[r] = 1.f / __shfl(l, quad * 4 + r);
#pragma unroll
    for (int dblk = 0; dblk < 4; ++dblk) {
        int c = h * 64 + dblk * 16 + (lane & 15);
        int kc = c >> 5, cc = c & 31;
#pragma unroll
        for (int r = 0; r < 4; ++r) {
            int t = qt * 64 + wq * 16 + quad * 4 + r;
            int m = b * T_ + t;
            int mt = m >> 7, rr = m & 127;
            int p = (cc >> 3) ^ ((rr >> 1) & 3);
            yt[(((size_t)mt * 32 + kc) << 12) + (rr << 5) + p * 8 + (cc & 7)] =
                f2bf(o[dblk][r] * linv[r]);
        }
    }
}

extern "C" void kernel_launch(void* const* d_in, const int* in_sizes, int n_in,
                              void* d_out, int out_size, void* d_ws, size_t ws_size,
                              hipStream_t stream) {
    (void)in_sizes; (void)n_in; (void)out_size; (void)ws_size;
    const float* x      = (const float*)d_in[0];
    const float* ext    = (const float*)d_in[1];
    const float* W_attn = (const float*)d_in[2];
    const float* b_attn = (const float*)d_in[3];
    const float* W_proj = (const float*)d_in[4];
    const float* b_proj = (const float*)d_in[5];
    float* out = (float*)d_out;

    unsigned short* x_tl  = (unsigned short*)d_ws;           // [32][32][128][32]
    unsigned short* WtA   = x_tl + 4194304;                  // [24][32][128][32]
    unsigned short* WtP   = WtA + 3145728;                   // [8][32][128][32]
    unsigned short* q_ws  = WtP + 1048576;                   // [bh][t][64] pre-scaled
    unsigned short* k_ws  = q_ws + 4194304;                  // [bh][s][64] swz
    unsigned short* v_tl  = k_ws + 4718592;                  // [bh][36][64][64] swz
    unsigned short* y_tl  = v_tl + 4718592;                  // [32][32][128][32]

    dim3 blk(256);
    prep_all<<<7168, blk, 0, stream>>>(x, W_attn, W_proj, ext,
                                       x_tl, WtA, WtP, k_ws, v_tl);
    qkv_gemm<<<dim3(24, 32), blk, 0, stream>>>(
        x_tl, WtA, b_attn, q_ws, k_ws, v_tl);
    flash_mfma<<<dim3(16, H_, B_), dim3(512), 0, stream>>>(q_ws, k_ws, v_tl, y_tl);
    proj_gemm<<<dim3(8, 64), blk, 0, stream>>>(y_tl, WtP, b_proj, out);
}